// Round 1
// baseline (253.850 us; speedup 1.0000x reference)
//
#include <hip/hip_runtime.h>

// GraphAttention: B=4, N=2048, F=256, H=8, F_=64; out [B, N, 512].
// 3 dispatches:
//  k_mask_conv: A->byte bitmask (+init maxn); X,W->bf16. 8 elems/thread,
//               32B/lane vectorized reads (G13), byte stores (same bit image
//               as the old u64 layout, LE).
//  k_gemm1    : h=X@W (MFMA) + att epilogue (att_s, packed exp table Tb,
//               per-bh max(att_n)) + LDS repack of h into MFMA-FRAGMENT
//               layout hswz[bh][jc][ct][lane][8]. Grid 1024 (16-row waves,
//               4 waves/SIMD; was 256 blocks = 1 wave/SIMD).
//  k_attn_av  : fused masked softmax @ h. Block = 256 thr = 4 waves; all
//               waves own the same 32 rows, each a 512-wide j-quarter ->
//               8192 waves (6-8/SIMD). P compute: p = max(k1*E, k2*E5)
//               (identical to the old (Ev>T0) select: exp monotone, equal at
//               z=0), mask via v_bfe_i32 sign-extend + AND, pack via
//               v_cvt_pk_bf16_f32 (num and denom use the same packed value,
//               rounding cancels in the ratio). LDS end-reduction, no atomics.
// History: r9 global-atomic j-split -> 425MB HBM (never); r11 VGPR-cap spills
// (keep cap >= ~84); r8-r13 ~106-111us -> fixed by fragment layout; r14
// (199.9us): VALUBusy 53%, Mfma 13%, occ 36% -> this round: VALU diet +
// occupancy on attn, occupancy on gemm1, vectorize mask_conv.
// Input dtype detected from A[0][0] (self-loop: fp32 word == 1.0f).

constexpr int GN  = 2048;
constexpr int GHF = 512;

using sh8    = __attribute__((ext_vector_type(8))) short;          // 8 bf16
using us4g   = __attribute__((ext_vector_type(4))) unsigned short;
using f32x4g = __attribute__((ext_vector_type(4))) float;
using u32x4g = __attribute__((ext_vector_type(4))) unsigned int;
using i32x4g = __attribute__((ext_vector_type(4))) int;

__device__ inline float gat_bf2f(unsigned short u) {
    union { unsigned int i; float f; } c; c.i = ((unsigned int)u) << 16; return c.f;
}
__device__ inline unsigned short gat_f2bf(float f) {
    union { float f; unsigned int i; } c; c.f = f;
    return (unsigned short)((c.i + 0x7fffu + ((c.i >> 16) & 1u)) >> 16); // RNE
}
__device__ inline int gat_isf32(const float* __restrict__ Aw) {
    float a = Aw[0];
    return (a == 0.0f) || (a == 1.0f);
}
__device__ inline unsigned int gat_enc(float f) {
    union { float f; unsigned int u; } c; c.f = f;
    return (c.u & 0x80000000u) ? ~c.u : (c.u | 0x80000000u);
}
__device__ inline float gat_dec(unsigned int e) {
    union { float f; unsigned int u; } c;
    c.u = (e & 0x80000000u) ? (e & 0x7fffffffu) : ~e;
    return c.f;
}
// fragment-layout accessor (scalar, for fallback paths):
// h[o][j] of head-slice -> flat elem index in hswz (per-bh base excluded)
__device__ inline size_t gat_hswz_idx(int o, int j) {
    int jc = j >> 5, quad = (j >> 3) & 3, e = j & 7;
    int lane = quad * 16 + (o & 15);
    return (((size_t)(jc * 4 + (o >> 4))) * 64 + lane) * 8 + e;
}

__global__ void GraphAttention_62981400429165_kernel() {}

// ---------------- workspace layout (bytes) ----------------
constexpr size_t OFF_HS   = 256;                       // hswz bf16      8 MB
constexpr size_t OFF_ATTS = OFF_HS   + 8388608;        // att_s f32    256 KB
constexpr size_t OFF_TB   = OFF_ATTS + 262144;         // packed E/E5  256 KB
constexpr size_t OFF_MASK = OFF_TB   + 262144;         // bitmask        2 MB
constexpr size_t OFF_MAXN = OFF_MASK + 2097152;        // 32 u32
constexpr size_t OFF_XC   = OFF_MAXN + 256;            // X bf16         4 MB
constexpr size_t OFF_WC   = OFF_XC   + 4194304;        // W bf16       256 KB

// --------------------------------------------------------------------------
// k_mask_conv: blocks 0..8191: A->mask bytes (+block 0 inits maxn).
// 8192..9215: X->bf16. 9216..9279: W->bf16. 8 elems per thread.
// --------------------------------------------------------------------------
__global__ __launch_bounds__(256) void k_mask_conv(const void* __restrict__ Araw,
                                                   const void* __restrict__ Xraw,
                                                   const void* __restrict__ Wraw,
                                                   unsigned long long* __restrict__ mask,
                                                   unsigned int* __restrict__ maxn_enc,
                                                   unsigned short* __restrict__ Xc,
                                                   unsigned short* __restrict__ Wc) {
    int tid = threadIdx.x, blk = blockIdx.x;
    int isf = gat_isf32((const float*)Araw);
    if (blk < 8192) {
        if (blk == 0 && tid < 32) maxn_enc[tid] = 0u;
        size_t i8 = ((size_t)blk * 256 + tid) * 8;
        unsigned int byte = 0;
        if (isf) {
            f32x4g v0 = *(const f32x4g*)((const float*)Araw + i8);
            f32x4g v1 = *(const f32x4g*)((const float*)Araw + i8 + 4);
#pragma unroll
            for (int e = 0; e < 4; e++) {
                byte |= (v0[e] != 0.0f ? 1u : 0u) << e;
                byte |= (v1[e] != 0.0f ? 1u : 0u) << (e + 4);
            }
        } else {
            u32x4g v = *(const u32x4g*)((const unsigned short*)Araw + i8);
#pragma unroll
            for (int w = 0; w < 4; w++) {
                byte |= ((v[w] & 0xffffu) != 0u ? 1u : 0u) << (2 * w);
                byte |= ((v[w] >> 16) != 0u ? 1u : 0u) << (2 * w + 1);
            }
        }
        ((unsigned char*)mask)[i8 >> 3] = (unsigned char)byte;
    } else if (blk < 9216) {
        size_t i8 = ((size_t)(blk - 8192) * 256 + tid) * 8;
        if (isf) {
            f32x4g v0 = *(const f32x4g*)((const float*)Xraw + i8);
            f32x4g v1 = *(const f32x4g*)((const float*)Xraw + i8 + 4);
            us4g lo, hi;
#pragma unroll
            for (int e = 0; e < 4; e++) { lo[e] = gat_f2bf(v0[e]); hi[e] = gat_f2bf(v1[e]); }
            *(us4g*)&Xc[i8]     = lo;
            *(us4g*)&Xc[i8 + 4] = hi;
        } else {
            *(u32x4g*)&Xc[i8] = *(const u32x4g*)((const unsigned short*)Xraw + i8);
        }
    } else {
        size_t i8 = ((size_t)(blk - 9216) * 256 + tid) * 8;
        if (isf) {
            f32x4g v0 = *(const f32x4g*)((const float*)Wraw + i8);
            f32x4g v1 = *(const f32x4g*)((const float*)Wraw + i8 + 4);
            us4g lo, hi;
#pragma unroll
            for (int e = 0; e < 4; e++) { lo[e] = gat_f2bf(v0[e]); hi[e] = gat_f2bf(v1[e]); }
            *(us4g*)&Wc[i8]     = lo;
            *(us4g*)&Wc[i8 + 4] = hi;
        } else {
            *(u32x4g*)&Wc[i8] = *(const u32x4g*)((const unsigned short*)Wraw + i8);
        }
    }
}

// --------------------------------------------------------------------------
// k_gemm1: h = X @ W per (b,h) + att epilogue + fragment-layout repack.
// grid 1024 (bh*32+it) x 256 (4 waves x 16 rows = 64 rows/block).
// 4 blocks/CU -> 4 waves/SIMD (was 1).
// --------------------------------------------------------------------------
constexpr int LDW = 264;
__global__ __launch_bounds__(256) void k_gemm1(const unsigned short* __restrict__ Xc,
                                               const unsigned short* __restrict__ Wc,
                                               const void* __restrict__ aSraw,
                                               const void* __restrict__ aNraw,
                                               const float* __restrict__ Aw,
                                               unsigned short* __restrict__ hswz,
                                               float* __restrict__ att_s,
                                               unsigned int* __restrict__ Tb,
                                               unsigned int* __restrict__ maxn_enc) {
    int blk = blockIdx.x;
    int bh = blk >> 5, it = blk & 31;
    int b = bh >> 3, hh = bh & 7;
    int isf = gat_isf32(Aw);
    __shared__ unsigned short Wt[64 * LDW];          // reused as CtT after K-loop
    {   // vectorized transpose staging: thread (k=tid>>3 in [0,32), cg=tid&7)
        int cg = threadIdx.x & 7, kb = threadIdx.x >> 3;
        for (int kk = 0; kk < 256; kk += 32) {
            int k = kk + kb;
            sh8 v = *(const sh8*)&Wc[((size_t)hh * 256 + k) * 64 + cg * 8];
#pragma unroll
            for (int e = 0; e < 8; e++)
                Wt[(cg * 8 + e) * LDW + k] = (unsigned short)v[e];
        }
    }
    __syncthreads();
#if defined(__gfx950__)
    int wave = threadIdx.x >> 6, lane = threadIdx.x & 63;
    int lrw = lane & 15, quad = lane >> 4;
    int row0 = it * 64 + wave * 16;
    f32x4g acc[4] = {};
    for (int k0 = 0; k0 < 256; k0 += 32) {
        sh8 a = *(const sh8*)&Xc[((size_t)(b * GN) + row0 + lrw) * 256 + k0 + quad * 8];
        sh8 w[4];
#pragma unroll
        for (int ct = 0; ct < 4; ct++)
            w[ct] = *(const sh8*)&Wt[(ct * 16 + lrw) * LDW + k0 + quad * 8];
#pragma unroll
        for (int ct = 0; ct < 4; ct++)
            acc[ct] = __builtin_amdgcn_mfma_f32_16x16x32_bf16(a, w[ct], acc[ct], 0, 0, 0);
    }
    // ---- att epilogue (register-only): att_s, packed table, maxn ----
    float as_l[4], an_l[4];
#pragma unroll
    for (int ct = 0; ct < 4; ct++) {
        int col = hh * 64 + ct * 16 + lrw;
        as_l[ct] = isf ? ((const float*)aSraw)[col] : gat_bf2f(((const unsigned short*)aSraw)[col]);
        an_l[ct] = isf ? ((const float*)aNraw)[col] : gat_bf2f(((const unsigned short*)aNraw)[col]);
    }
    float wmax = -3e38f;
#pragma unroll
    for (int r = 0; r < 4; r++) {
        float ps = acc[0][r] * as_l[0] + acc[1][r] * as_l[1]
                 + acc[2][r] * as_l[2] + acc[3][r] * as_l[3];
        float pn = acc[0][r] * an_l[0] + acc[1][r] * an_l[1]
                 + acc[2][r] * an_l[2] + acc[3][r] * an_l[3];
        for (int off = 1; off < 16; off <<= 1) {
            ps += __shfl_xor(ps, off);
            pn += __shfl_xor(pn, off);
        }
        int row = row0 + quad * 4 + r;
        if (lrw == 0) {
            att_s[bh * GN + row] = ps;
            Tb[bh * GN + row] = ((unsigned int)gat_f2bf(__expf(pn)) << 16)
                              | (unsigned int)gat_f2bf(__expf(0.2f * pn));
        }
        wmax = fmaxf(wmax, pn);
    }
    wmax = fmaxf(wmax, __shfl_xor(wmax, 16));
    wmax = fmaxf(wmax, __shfl_xor(wmax, 32));
    if (lane == 0) atomicMax(&maxn_enc[bh], gat_enc(wmax));
    // ---- repack: acc -> LDS CtT[o][nloc] -> hswz fragment layout ----
    __syncthreads();                                  // Wt reads done; reuse as CtT
    unsigned short* CtT = Wt;                         // [o][nloc], stride LDW
#pragma unroll
    for (int ct = 0; ct < 4; ct++) {
        int o = ct * 16 + lrw;
        int nloc = wave * 16 + quad * 4;
        us4g v;
        v[0] = gat_f2bf(acc[ct][0]);
        v[1] = gat_f2bf(acc[ct][1]);
        v[2] = gat_f2bf(acc[ct][2]);
        v[3] = gat_f2bf(acc[ct][3]);
        *(us4g*)&CtT[o * LDW + nloc] = v;
    }
    __syncthreads();
    // 512 fragment-lane items (2 jc_loc x 4 ct x 64 lane), 2 per thread
#pragma unroll
    for (int k = 0; k < 2; k++) {
        int id = k * 256 + threadIdx.x;
        int ln = id & 63, t = id >> 6;               // t in [0,8)
        int jc_loc = t >> 2, ct = t & 3;
        int lrw2 = ln & 15, quad2 = ln >> 4;
        int o = ct * 16 + lrw2;
        int nloc = jc_loc * 32 + quad2 * 8;
        sh8 v = *(const sh8*)&CtT[o * LDW + nloc];
        size_t dst = ((((size_t)(bh * 64 + it * 2 + jc_loc)) * 4 + ct) * 64 + ln) * 8;
        *(sh8*)&hswz[dst] = v;
    }
#else
    // fallback: 64 rows/block, thread per row, scalar
    if (threadIdx.x < 64) {
        int row = it * 64 + threadIdx.x;
        float hrow[64];
        for (int col = 0; col < 64; col++) {
            float sacc = 0.f;
            for (int k = 0; k < 256; k++)
                sacc += gat_bf2f(Xc[((size_t)(b * GN) + row) * 256 + k]) * gat_bf2f(Wt[col * LDW + k]);
            hrow[col] = sacc;
        }
        size_t base = (size_t)bh * 64 * GN;          // elems per bh slice = 64*2048
        for (int col = 0; col < 64; col++)
            hswz[base + gat_hswz_idx(col, row)] = gat_f2bf(hrow[col]);
        float ps = 0.f, pn = 0.f;
        for (int col = 0; col < 64; col++) {
            float as = isf ? ((const float*)aSraw)[hh * 64 + col] : gat_bf2f(((const unsigned short*)aSraw)[hh * 64 + col]);
            float an = isf ? ((const float*)aNraw)[hh * 64 + col] : gat_bf2f(((const unsigned short*)aNraw)[hh * 64 + col]);
            ps += hrow[col] * as;
            pn += hrow[col] * an;
        }
        att_s[bh * GN + row] = ps;
        Tb[bh * GN + row] = ((unsigned int)gat_f2bf(__expf(pn)) << 16)
                          | (unsigned int)gat_f2bf(__expf(0.2f * pn));
        atomicMax(&maxn_enc[bh], gat_enc(pn));
    }
#endif
}

// --------------------------------------------------------------------------
// k_attn_av: out = relu( softmax(P) @ h ). grid 2048 (bh = blk&31 for XCD
// locality, it = blk>>5 -> 32 rows), 256 thr = 4 waves; wave w covers j in
// [w*512, +512) for the SAME 32 rows. B-frags are lane-linear 16B loads
// from hswz. LDS end-reduction, no atomics. Table-based P:
// p = max(k1*E, k2*E5) (== old (E>T0) select), bfe_i32 sign-mask for A-mask,
// v_cvt_pk_bf16_f32 pack.
// --------------------------------------------------------------------------
__global__ __launch_bounds__(256, 6) void k_attn_av(const unsigned int* __restrict__ mask32,
                                                    const unsigned short* __restrict__ hswz,
                                                    const float* __restrict__ att_s,
                                                    const unsigned int* __restrict__ Tb,
                                                    const unsigned int* __restrict__ maxn_enc,
                                                    const float* __restrict__ Aw,
                                                    void* __restrict__ outv) {
    int blk = blockIdx.x;
    int bh = blk & 31, it = blk >> 5;
    int b = bh >> 3, hh = bh & 7;
    int i0 = it * 32;
    int tid = threadIdx.x;
    int isf = gat_isf32(Aw);
    float maxn = gat_dec(maxn_enc[bh]);
    const unsigned int* Tp = Tb + (size_t)bh * GN;
#if defined(__gfx950__)
    int wave = tid >> 6, lane = tid & 63, lrw = lane & 15, quad = lane >> 4;
    int kq = quad * 8;
    int j0 = wave * 512;                             // this wave's j-quarter
    // per-wave fragment base: jc group wave*16, lane-linear
    const unsigned short* hs = hswz + ((size_t)(bh * 64) + wave * 16) * 2048 + lane * 8;
    float k1[2], k2[2];
    const unsigned int* mrf[2];
    for (int f = 0; f < 2; f++) {
        int row = i0 + f * 16 + lrw;
        float s = att_s[bh * GN + row];
        float z = s + maxn;
        float c = fmaxf(z, 0.2f * z);                // >= true row max
        k1[f] = __expf(s - c);
        k2[f] = __expf(0.2f * s - c);
        mrf[f] = mask32 + ((size_t)(b * GN) + row) * 64 + wave * 16;
    }
    f32x4g acc[2][4] = {};
    f32x4g accl[2] = {};
    sh8 ones;
#pragma unroll
    for (int e = 0; e < 8; e++) ones[e] = (short)0x3f80;  // bf16 1.0

#pragma unroll 1
    for (int jg = 0; jg < 4; jg++) {                 // 4 groups x 4 jc
        u32x4g m0 = *(const u32x4g*)&mrf[0][jg * 4];
        u32x4g m1 = *(const u32x4g*)&mrf[1][jg * 4];
#pragma unroll
        for (int sj = 0; sj < 4; sj++) {
            int jc = jg * 4 + sj;
            int jq = j0 + jc * 32 + kq;
            u32x4g tA = *(const u32x4g*)&Tp[jq];
            u32x4g tB = *(const u32x4g*)&Tp[jq + 4];
            const unsigned short* hp = hs + jc * 2048;
            sh8 b0 = *(const sh8*)&hp[0];            // ct=0 (lane-linear 16B)
            sh8 b1 = *(const sh8*)&hp[512];          // ct=1
            sh8 b2 = *(const sh8*)&hp[1024];         // ct=2
            sh8 b3 = *(const sh8*)&hp[1536];         // ct=3
            unsigned int w0 = m0[sj] >> kq;
            unsigned int w1 = m1[sj] >> kq;
            unsigned int q0[8], q1[8];
#pragma unroll
            for (int e = 0; e < 8; e++) {
                unsigned int word = (e < 4) ? tA[e] : tB[e - 4];
                float Ev  = __uint_as_float(word & 0xffff0000u);
                float E5v = __uint_as_float(word << 16);
                // exp monotone: max(exp(z), exp(.2z)) == exp(leakyrelu(z))
                float p0 = fmaxf(k1[0] * Ev, k2[0] * E5v);
                float p1 = fmaxf(k1[1] * Ev, k2[1] * E5v);
                // v_bfe_i32: bit e -> 0 / 0xffffffff, AND-mask (no vcc chain)
                unsigned int s0 = (unsigned int)__builtin_amdgcn_sbfe((int)w0, (unsigned)e, 1u);
                unsigned int s1 = (unsigned int)__builtin_amdgcn_sbfe((int)w1, (unsigned)e, 1u);
                q0[e] = __float_as_uint(p0) & s0;
                q1[e] = __float_as_uint(p1) & s1;
            }
            i32x4g f0, f1;
#pragma unroll
            for (int pp = 0; pp < 4; pp++) {         // RNE pack, 1 instr/pair
                unsigned int r0, r1;
                asm("v_cvt_pk_bf16_f32 %0, %1, %2"
                    : "=v"(r0)
                    : "v"(__uint_as_float(q0[2 * pp])), "v"(__uint_as_float(q0[2 * pp + 1])));
                asm("v_cvt_pk_bf16_f32 %0, %1, %2"
                    : "=v"(r1)
                    : "v"(__uint_as_float(q1[2 * pp])), "v"(__uint_as_float(q1[2 * pp + 1])));
                f0[pp] = (int)r0;
                f1[pp] = (int)r1;
            }
            sh8 af0 = *(sh8*)&f0;
            sh8 af1 = *(sh8*)&f1;
            acc[0][0] = __builtin_amdgcn_mfma_f32_16x16x32_bf16(af0, b0, acc[0][0], 0, 0, 0);
            acc[1][0] = __builtin_amdgcn_mfma_f32_16x16x32_bf16(af1, b0, acc[1][0], 0, 0, 0);
            acc[0][1] = __builtin_amdgcn_mfma_f32_16x16x32_bf16(af0, b1, acc[0][1], 0, 0, 0);
            acc[1][1] = __builtin_amdgcn_mfma_f32_16x16x32_bf16(af1, b1, acc[1][1], 0, 0, 0);
            acc[0][2] = __builtin_amdgcn_mfma_f32_16x16x32_bf16(af0, b2, acc[0][2], 0, 0, 0);
            acc[1][2] = __builtin_amdgcn_mfma_f32_16x16x32_bf16(af1, b2, acc[1][2], 0, 0, 0);
            acc[0][3] = __builtin_amdgcn_mfma_f32_16x16x32_bf16(af0, b3, acc[0][3], 0, 0, 0);
            acc[1][3] = __builtin_amdgcn_mfma_f32_16x16x32_bf16(af1, b3, acc[1][3], 0, 0, 0);
            accl[0] = __builtin_amdgcn_mfma_f32_16x16x32_bf16(af0, ones, accl[0], 0, 0, 0);
            accl[1] = __builtin_amdgcn_mfma_f32_16x16x32_bf16(af1, ones, accl[1], 0, 0, 0);
        }
    }
    // ---- end-of-kernel reduction across the 4 j-quarter waves (LDS) ----
    __shared__ float lred[4 * 32];                   // [wave][row32]
    __shared__ float lsum[32];                       // 1/l per row
    __shared__ float red[4 * 2 * 16 * 17];           // [wave][f][r16][c16 pad17]
    if (lrw == 0) {
#pragma unroll
        for (int f = 0; f < 2; f++)
#pragma unroll
            for (int r = 0; r < 4; r++)
                lred[wave * 32 + f * 16 + quad * 4 + r] = accl[f][r];
    }
    __syncthreads();
    if (tid < 32)
        lsum[tid] = 1.0f / (lred[tid] + lred[32 + tid] + lred[64 + tid] + lred[96 + tid]);
    __syncthreads();
    for (int ct = 0; ct < 4; ct++) {
#pragma unroll
        for (int f = 0; f < 2; f++)
#pragma unroll
            for (int r = 0; r < 4; r++)
                red[wave * 544 + f * 272 + (quad * 4 + r) * 17 + lrw] = acc[f][ct][r];
        __syncthreads();
#pragma unroll
        for (int k = 0; k < 2; k++) {
            int pos = k * 256 + tid;                 // [0,512): f(1b) r16(4b) c16(4b)
            int f = pos >> 8, r16 = (pos >> 4) & 15, c16 = pos & 15;
            int bse = f * 272 + r16 * 17 + c16;
            float sum = red[bse] + red[bse + 544] + red[bse + 1088] + red[bse + 1632];
            float v = sum * lsum[f * 16 + r16];
            v = v > 0.f ? v : 0.f;
            int row = i0 + f * 16 + r16;
            size_t o = ((size_t)(b * GN) + row) * GHF + hh * 64 + ct * 16 + c16;
            if (isf) ((float*)outv)[o] = v;
            else     ((unsigned short*)outv)[o] = gat_f2bf(v);
        }
        __syncthreads();
    }
#else
    // correctness-only fallback: thread -> (row = tid>>3, 8-col eighth)
    int row = i0 + (tid >> 3), chh = (tid & 7) * 8;
    const unsigned short* hbb = hswz + (size_t)(bh * 64) * GN;  // per-bh slice
    const unsigned int* mr = mask32 + ((size_t)(b * GN) + row) * 64;
    float s = att_s[bh * GN + row];
    float z = s + maxn;
    float c = fmaxf(z, 0.2f * z);
    float k1 = __expf(s - c), k2 = __expf(0.2f * s - c);
    float l = 0.f;
    float accS[8] = {};
    for (int j = 0; j < GN; j++) {
        if (!((mr[j >> 5] >> (j & 31)) & 1u)) continue;
        unsigned int word = Tp[j];
        float Ev  = __uint_as_float(word & 0xffff0000u);
        float E5v = __uint_as_float(word << 16);
        float p = fmaxf(k1 * Ev, k2 * E5v);
        union { float f; unsigned int u; } t; t.f = p; t.u &= 0xffff0000u;
        l += t.f;
        for (int cc = 0; cc < 8; cc++)
            accS[cc] += t.f * gat_bf2f(hbb[gat_hswz_idx(chh + cc, j)]);
    }
    float li = 1.0f / l;
    for (int cc = 0; cc < 8; cc++) {
        float v = accS[cc] * li; v = v > 0.f ? v : 0.f;
        size_t oi = ((size_t)(b * GN) + row) * GHF + hh * 64 + chh + cc;
        if (isf) ((float*)outv)[oi] = v;
        else     ((unsigned short*)outv)[oi] = gat_f2bf(v);
    }
#endif
}

// --------------------------------------------------------------------------
extern "C" void kernel_launch(void* const* d_in, const int* in_sizes, int n_in,
                              void* d_out, int out_size, void* d_ws, size_t ws_size,
                              hipStream_t stream) {
    const void* X  = d_in[0];
    const void* A  = d_in[1];
    const void* W  = d_in[2];
    const void* aS = d_in[3];
    const void* aN = d_in[4];

    char* ws = (char*)d_ws;
    unsigned short* hswz = (unsigned short*)(ws + OFF_HS);
    float* att_s = (float*)(ws + OFF_ATTS);
    unsigned int* Tb = (unsigned int*)(ws + OFF_TB);
    unsigned long long* mask = (unsigned long long*)(ws + OFF_MASK);
    unsigned int* maxn_enc = (unsigned int*)(ws + OFF_MAXN);
    unsigned short* Xc = (unsigned short*)(ws + OFF_XC);
    unsigned short* Wc = (unsigned short*)(ws + OFF_WC);

    k_mask_conv<<<9280, 256, 0, stream>>>(A, X, W, mask, maxn_enc, Xc, Wc);
    k_gemm1<<<1024, 256, 0, stream>>>(Xc, Wc, aS, aN, (const float*)A,
                                      hswz, att_s, Tb, maxn_enc);
    k_attn_av<<<2048, 256, 0, stream>>>((const unsigned int*)mask, hswz,
                                        att_s, Tb, maxn_enc,
                                        (const float*)A, d_out);
}

// Round 2
// 202.878 us; speedup vs baseline: 1.2512x; 1.2512x over previous
//
#include <hip/hip_runtime.h>

// GraphAttention: B=4, N=2048, F=256, H=8, F_=64; out [B, N, 512].
// 3 dispatches:
//  k_mask_conv: A->byte bitmask (+init maxn); X,W->bf16. 8 elems/thread,
//               32B/lane vectorized reads (G13), byte stores (same bit image
//               as the old u64 layout, LE).
//  k_gemm1    : h=X@W (MFMA) + att epilogue (att_s, packed exp table Tb,
//               per-bh max(att_n)) + LDS repack of h into MFMA-FRAGMENT
//               layout hswz[bh][jc][ct][lane][8]. Grid 1024 (16-row waves).
//  k_attn_av  : fused masked softmax @ h. Block = 256 thr = 4 waves; all
//               waves own the same 32 rows, each a 512-wide j-quarter ->
//               8192 waves. P compute: p = max(k1*E, k2*E5) (== the exact
//               (Ev>T0) select: exp monotone, equal at z=0), mask via
//               v_bfe_i32 sign-extend + AND, pack via v_cvt_pk_bf16_f32
//               (num and denom share the packed value, rounding cancels in
//               the ratio). LDS end-reduction, no atomics.
// History: r9 global-atomic j-split -> 425MB HBM (never); r11 AND r15:
// __launch_bounds__ min-waves arg 6 forced VGPR cap 40 -> inner-loop spills
// -> 230-380MB HBM, attn 108us. KEEP VGPR CAP >= 128 (2nd arg <= 4 for
// 256-thr blocks). r14 (199.9us): VALUBusy 53%, Mfma 13%, occ 36%;
// r15 (253.8us): spill regression, fixed here by (256,4).
// Input dtype detected from A[0][0] (self-loop: fp32 word == 1.0f).

constexpr int GN  = 2048;
constexpr int GHF = 512;

using sh8    = __attribute__((ext_vector_type(8))) short;          // 8 bf16
using us4g   = __attribute__((ext_vector_type(4))) unsigned short;
using f32x4g = __attribute__((ext_vector_type(4))) float;
using u32x4g = __attribute__((ext_vector_type(4))) unsigned int;
using i32x4g = __attribute__((ext_vector_type(4))) int;

__device__ inline float gat_bf2f(unsigned short u) {
    union { unsigned int i; float f; } c; c.i = ((unsigned int)u) << 16; return c.f;
}
__device__ inline unsigned short gat_f2bf(float f) {
    union { float f; unsigned int i; } c; c.f = f;
    return (unsigned short)((c.i + 0x7fffu + ((c.i >> 16) & 1u)) >> 16); // RNE
}
__device__ inline int gat_isf32(const float* __restrict__ Aw) {
    float a = Aw[0];
    return (a == 0.0f) || (a == 1.0f);
}
__device__ inline unsigned int gat_enc(float f) {
    union { float f; unsigned int u; } c; c.f = f;
    return (c.u & 0x80000000u) ? ~c.u : (c.u | 0x80000000u);
}
__device__ inline float gat_dec(unsigned int e) {
    union { float f; unsigned int u; } c;
    c.u = (e & 0x80000000u) ? (e & 0x7fffffffu) : ~e;
    return c.f;
}
// fragment-layout accessor (scalar, for fallback paths):
// h[o][j] of head-slice -> flat elem index in hswz (per-bh base excluded)
__device__ inline size_t gat_hswz_idx(int o, int j) {
    int jc = j >> 5, quad = (j >> 3) & 3, e = j & 7;
    int lane = quad * 16 + (o & 15);
    return (((size_t)(jc * 4 + (o >> 4))) * 64 + lane) * 8 + e;
}

__global__ void GraphAttention_62981400429165_kernel() {}

// ---------------- workspace layout (bytes) ----------------
constexpr size_t OFF_HS   = 256;                       // hswz bf16      8 MB
constexpr size_t OFF_ATTS = OFF_HS   + 8388608;        // att_s f32    256 KB
constexpr size_t OFF_TB   = OFF_ATTS + 262144;         // packed E/E5  256 KB
constexpr size_t OFF_MASK = OFF_TB   + 262144;         // bitmask        2 MB
constexpr size_t OFF_MAXN = OFF_MASK + 2097152;        // 32 u32
constexpr size_t OFF_XC   = OFF_MAXN + 256;            // X bf16         4 MB
constexpr size_t OFF_WC   = OFF_XC   + 4194304;        // W bf16       256 KB

// --------------------------------------------------------------------------
// k_mask_conv: blocks 0..8191: A->mask bytes (+block 0 inits maxn).
// 8192..9215: X->bf16. 9216..9279: W->bf16. 8 elems per thread.
// --------------------------------------------------------------------------
__global__ __launch_bounds__(256) void k_mask_conv(const void* __restrict__ Araw,
                                                   const void* __restrict__ Xraw,
                                                   const void* __restrict__ Wraw,
                                                   unsigned long long* __restrict__ mask,
                                                   unsigned int* __restrict__ maxn_enc,
                                                   unsigned short* __restrict__ Xc,
                                                   unsigned short* __restrict__ Wc) {
    int tid = threadIdx.x, blk = blockIdx.x;
    int isf = gat_isf32((const float*)Araw);
    if (blk < 8192) {
        if (blk == 0 && tid < 32) maxn_enc[tid] = 0u;
        size_t i8 = ((size_t)blk * 256 + tid) * 8;
        unsigned int byte = 0;
        if (isf) {
            f32x4g v0 = *(const f32x4g*)((const float*)Araw + i8);
            f32x4g v1 = *(const f32x4g*)((const float*)Araw + i8 + 4);
#pragma unroll
            for (int e = 0; e < 4; e++) {
                byte |= (v0[e] != 0.0f ? 1u : 0u) << e;
                byte |= (v1[e] != 0.0f ? 1u : 0u) << (e + 4);
            }
        } else {
            u32x4g v = *(const u32x4g*)((const unsigned short*)Araw + i8);
#pragma unroll
            for (int w = 0; w < 4; w++) {
                byte |= ((v[w] & 0xffffu) != 0u ? 1u : 0u) << (2 * w);
                byte |= ((v[w] >> 16) != 0u ? 1u : 0u) << (2 * w + 1);
            }
        }
        ((unsigned char*)mask)[i8 >> 3] = (unsigned char)byte;
    } else if (blk < 9216) {
        size_t i8 = ((size_t)(blk - 8192) * 256 + tid) * 8;
        if (isf) {
            f32x4g v0 = *(const f32x4g*)((const float*)Xraw + i8);
            f32x4g v1 = *(const f32x4g*)((const float*)Xraw + i8 + 4);
            us4g lo, hi;
#pragma unroll
            for (int e = 0; e < 4; e++) { lo[e] = gat_f2bf(v0[e]); hi[e] = gat_f2bf(v1[e]); }
            *(us4g*)&Xc[i8]     = lo;
            *(us4g*)&Xc[i8 + 4] = hi;
        } else {
            *(u32x4g*)&Xc[i8] = *(const u32x4g*)((const unsigned short*)Xraw + i8);
        }
    } else {
        size_t i8 = ((size_t)(blk - 9216) * 256 + tid) * 8;
        if (isf) {
            f32x4g v0 = *(const f32x4g*)((const float*)Wraw + i8);
            f32x4g v1 = *(const f32x4g*)((const float*)Wraw + i8 + 4);
            us4g lo, hi;
#pragma unroll
            for (int e = 0; e < 4; e++) { lo[e] = gat_f2bf(v0[e]); hi[e] = gat_f2bf(v1[e]); }
            *(us4g*)&Wc[i8]     = lo;
            *(us4g*)&Wc[i8 + 4] = hi;
        } else {
            *(u32x4g*)&Wc[i8] = *(const u32x4g*)((const unsigned short*)Wraw + i8);
        }
    }
}

// --------------------------------------------------------------------------
// k_gemm1: h = X @ W per (b,h) + att epilogue + fragment-layout repack.
// grid 1024 (bh*32+it) x 256 (4 waves x 16 rows = 64 rows/block).
// --------------------------------------------------------------------------
constexpr int LDW = 264;
__global__ __launch_bounds__(256) void k_gemm1(const unsigned short* __restrict__ Xc,
                                               const unsigned short* __restrict__ Wc,
                                               const void* __restrict__ aSraw,
                                               const void* __restrict__ aNraw,
                                               const float* __restrict__ Aw,
                                               unsigned short* __restrict__ hswz,
                                               float* __restrict__ att_s,
                                               unsigned int* __restrict__ Tb,
                                               unsigned int* __restrict__ maxn_enc) {
    int blk = blockIdx.x;
    int bh = blk >> 5, it = blk & 31;
    int b = bh >> 3, hh = bh & 7;
    int isf = gat_isf32(Aw);
    __shared__ unsigned short Wt[64 * LDW];          // reused as CtT after K-loop
    {   // vectorized transpose staging: thread (k=tid>>3 in [0,32), cg=tid&7)
        int cg = threadIdx.x & 7, kb = threadIdx.x >> 3;
        for (int kk = 0; kk < 256; kk += 32) {
            int k = kk + kb;
            sh8 v = *(const sh8*)&Wc[((size_t)hh * 256 + k) * 64 + cg * 8];
#pragma unroll
            for (int e = 0; e < 8; e++)
                Wt[(cg * 8 + e) * LDW + k] = (unsigned short)v[e];
        }
    }
    __syncthreads();
#if defined(__gfx950__)
    int wave = threadIdx.x >> 6, lane = threadIdx.x & 63;
    int lrw = lane & 15, quad = lane >> 4;
    int row0 = it * 64 + wave * 16;
    f32x4g acc[4] = {};
    for (int k0 = 0; k0 < 256; k0 += 32) {
        sh8 a = *(const sh8*)&Xc[((size_t)(b * GN) + row0 + lrw) * 256 + k0 + quad * 8];
        sh8 w[4];
#pragma unroll
        for (int ct = 0; ct < 4; ct++)
            w[ct] = *(const sh8*)&Wt[(ct * 16 + lrw) * LDW + k0 + quad * 8];
#pragma unroll
        for (int ct = 0; ct < 4; ct++)
            acc[ct] = __builtin_amdgcn_mfma_f32_16x16x32_bf16(a, w[ct], acc[ct], 0, 0, 0);
    }
    // ---- att epilogue (register-only): att_s, packed table, maxn ----
    float as_l[4], an_l[4];
#pragma unroll
    for (int ct = 0; ct < 4; ct++) {
        int col = hh * 64 + ct * 16 + lrw;
        as_l[ct] = isf ? ((const float*)aSraw)[col] : gat_bf2f(((const unsigned short*)aSraw)[col]);
        an_l[ct] = isf ? ((const float*)aNraw)[col] : gat_bf2f(((const unsigned short*)aNraw)[col]);
    }
    float wmax = -3e38f;
#pragma unroll
    for (int r = 0; r < 4; r++) {
        float ps = acc[0][r] * as_l[0] + acc[1][r] * as_l[1]
                 + acc[2][r] * as_l[2] + acc[3][r] * as_l[3];
        float pn = acc[0][r] * an_l[0] + acc[1][r] * an_l[1]
                 + acc[2][r] * an_l[2] + acc[3][r] * an_l[3];
        for (int off = 1; off < 16; off <<= 1) {
            ps += __shfl_xor(ps, off);
            pn += __shfl_xor(pn, off);
        }
        int row = row0 + quad * 4 + r;
        if (lrw == 0) {
            att_s[bh * GN + row] = ps;
            Tb[bh * GN + row] = ((unsigned int)gat_f2bf(__expf(pn)) << 16)
                              | (unsigned int)gat_f2bf(__expf(0.2f * pn));
        }
        wmax = fmaxf(wmax, pn);
    }
    wmax = fmaxf(wmax, __shfl_xor(wmax, 16));
    wmax = fmaxf(wmax, __shfl_xor(wmax, 32));
    if (lane == 0) atomicMax(&maxn_enc[bh], gat_enc(wmax));
    // ---- repack: acc -> LDS CtT[o][nloc] -> hswz fragment layout ----
    __syncthreads();                                  // Wt reads done; reuse as CtT
    unsigned short* CtT = Wt;                         // [o][nloc], stride LDW
#pragma unroll
    for (int ct = 0; ct < 4; ct++) {
        int o = ct * 16 + lrw;
        int nloc = wave * 16 + quad * 4;
        us4g v;
        v[0] = gat_f2bf(acc[ct][0]);
        v[1] = gat_f2bf(acc[ct][1]);
        v[2] = gat_f2bf(acc[ct][2]);
        v[3] = gat_f2bf(acc[ct][3]);
        *(us4g*)&CtT[o * LDW + nloc] = v;
    }
    __syncthreads();
    // 512 fragment-lane items (2 jc_loc x 4 ct x 64 lane), 2 per thread
#pragma unroll
    for (int k = 0; k < 2; k++) {
        int id = k * 256 + threadIdx.x;
        int ln = id & 63, t = id >> 6;               // t in [0,8)
        int jc_loc = t >> 2, ct = t & 3;
        int lrw2 = ln & 15, quad2 = ln >> 4;
        int o = ct * 16 + lrw2;
        int nloc = jc_loc * 32 + quad2 * 8;
        sh8 v = *(const sh8*)&CtT[o * LDW + nloc];
        size_t dst = ((((size_t)(bh * 64 + it * 2 + jc_loc)) * 4 + ct) * 64 + ln) * 8;
        *(sh8*)&hswz[dst] = v;
    }
#else
    // fallback: 64 rows/block, thread per row, scalar
    if (threadIdx.x < 64) {
        int row = it * 64 + threadIdx.x;
        float hrow[64];
        for (int col = 0; col < 64; col++) {
            float sacc = 0.f;
            for (int k = 0; k < 256; k++)
                sacc += gat_bf2f(Xc[((size_t)(b * GN) + row) * 256 + k]) * gat_bf2f(Wt[col * LDW + k]);
            hrow[col] = sacc;
        }
        size_t base = (size_t)bh * 64 * GN;          // elems per bh slice = 64*2048
        for (int col = 0; col < 64; col++)
            hswz[base + gat_hswz_idx(col, row)] = gat_f2bf(hrow[col]);
        float ps = 0.f, pn = 0.f;
        for (int col = 0; col < 64; col++) {
            float as = isf ? ((const float*)aSraw)[hh * 64 + col] : gat_bf2f(((const unsigned short*)aSraw)[hh * 64 + col]);
            float an = isf ? ((const float*)aNraw)[hh * 64 + col] : gat_bf2f(((const unsigned short*)aNraw)[hh * 64 + col]);
            ps += hrow[col] * as;
            pn += hrow[col] * an;
        }
        att_s[bh * GN + row] = ps;
        Tb[bh * GN + row] = ((unsigned int)gat_f2bf(__expf(pn)) << 16)
                          | (unsigned int)gat_f2bf(__expf(0.2f * pn));
        atomicMax(&maxn_enc[bh], gat_enc(pn));
    }
#endif
}

// --------------------------------------------------------------------------
// k_attn_av: out = relu( softmax(P) @ h ). grid 2048 (bh = blk&31 for XCD
// locality, it = blk>>5 -> 32 rows), 256 thr = 4 waves; wave w covers j in
// [w*512, +512) for the SAME 32 rows. B-frags are lane-linear 16B loads
// from hswz. LDS end-reduction, no atomics. Table-based P:
// p = max(k1*E, k2*E5) (== old (E>T0) select), bfe_i32 sign-mask for A-mask,
// v_cvt_pk_bf16_f32 pack. launch_bounds (256,4): VGPR cap 128 — cap 40
// (from min-waves 6) spilled the inner loop (r11, r15).
// --------------------------------------------------------------------------
__global__ __launch_bounds__(256, 4) void k_attn_av(const unsigned int* __restrict__ mask32,
                                                    const unsigned short* __restrict__ hswz,
                                                    const float* __restrict__ att_s,
                                                    const unsigned int* __restrict__ Tb,
                                                    const unsigned int* __restrict__ maxn_enc,
                                                    const float* __restrict__ Aw,
                                                    void* __restrict__ outv) {
    int blk = blockIdx.x;
    int bh = blk & 31, it = blk >> 5;
    int b = bh >> 3, hh = bh & 7;
    int i0 = it * 32;
    int tid = threadIdx.x;
    int isf = gat_isf32(Aw);
    float maxn = gat_dec(maxn_enc[bh]);
    const unsigned int* Tp = Tb + (size_t)bh * GN;
#if defined(__gfx950__)
    int wave = tid >> 6, lane = tid & 63, lrw = lane & 15, quad = lane >> 4;
    int kq = quad * 8;
    int j0 = wave * 512;                             // this wave's j-quarter
    // per-wave fragment base: jc group wave*16, lane-linear
    const unsigned short* hs = hswz + ((size_t)(bh * 64) + wave * 16) * 2048 + lane * 8;
    float k1[2], k2[2];
    const unsigned int* mrf[2];
    for (int f = 0; f < 2; f++) {
        int row = i0 + f * 16 + lrw;
        float s = att_s[bh * GN + row];
        float z = s + maxn;
        float c = fmaxf(z, 0.2f * z);                // >= true row max
        k1[f] = __expf(s - c);
        k2[f] = __expf(0.2f * s - c);
        mrf[f] = mask32 + ((size_t)(b * GN) + row) * 64 + wave * 16;
    }
    f32x4g acc[2][4] = {};
    f32x4g accl[2] = {};
    sh8 ones;
#pragma unroll
    for (int e = 0; e < 8; e++) ones[e] = (short)0x3f80;  // bf16 1.0

#pragma unroll 1
    for (int jg = 0; jg < 4; jg++) {                 // 4 groups x 4 jc
        u32x4g m0 = *(const u32x4g*)&mrf[0][jg * 4];
        u32x4g m1 = *(const u32x4g*)&mrf[1][jg * 4];
#pragma unroll
        for (int sj = 0; sj < 4; sj++) {
            int jc = jg * 4 + sj;
            int jq = j0 + jc * 32 + kq;
            u32x4g tA = *(const u32x4g*)&Tp[jq];
            u32x4g tB = *(const u32x4g*)&Tp[jq + 4];
            const unsigned short* hp = hs + jc * 2048;
            sh8 b0 = *(const sh8*)&hp[0];            // ct=0 (lane-linear 16B)
            sh8 b1 = *(const sh8*)&hp[512];          // ct=1
            sh8 b2 = *(const sh8*)&hp[1024];         // ct=2
            sh8 b3 = *(const sh8*)&hp[1536];         // ct=3
            unsigned int w0 = m0[sj] >> kq;
            unsigned int w1 = m1[sj] >> kq;
            unsigned int q0[8], q1[8];
#pragma unroll
            for (int e = 0; e < 8; e++) {
                unsigned int word = (e < 4) ? tA[e] : tB[e - 4];
                float Ev  = __uint_as_float(word & 0xffff0000u);
                float E5v = __uint_as_float(word << 16);
                // exp monotone: max(exp(z), exp(.2z)) == exp(leakyrelu(z))
                float p0 = fmaxf(k1[0] * Ev, k2[0] * E5v);
                float p1 = fmaxf(k1[1] * Ev, k2[1] * E5v);
                // v_bfe_i32: bit e -> 0 / 0xffffffff, AND-mask (no vcc chain)
                unsigned int s0 = (unsigned int)__builtin_amdgcn_sbfe((int)w0, (unsigned)e, 1u);
                unsigned int s1 = (unsigned int)__builtin_amdgcn_sbfe((int)w1, (unsigned)e, 1u);
                q0[e] = __float_as_uint(p0) & s0;
                q1[e] = __float_as_uint(p1) & s1;
            }
            i32x4g f0, f1;
#pragma unroll
            for (int pp = 0; pp < 4; pp++) {         // RNE pack, 1 instr/pair
                unsigned int r0, r1;
                asm("v_cvt_pk_bf16_f32 %0, %1, %2"
                    : "=v"(r0)
                    : "v"(__uint_as_float(q0[2 * pp])), "v"(__uint_as_float(q0[2 * pp + 1])));
                asm("v_cvt_pk_bf16_f32 %0, %1, %2"
                    : "=v"(r1)
                    : "v"(__uint_as_float(q1[2 * pp])), "v"(__uint_as_float(q1[2 * pp + 1])));
                f0[pp] = (int)r0;
                f1[pp] = (int)r1;
            }
            sh8 af0 = *(sh8*)&f0;
            sh8 af1 = *(sh8*)&f1;
            acc[0][0] = __builtin_amdgcn_mfma_f32_16x16x32_bf16(af0, b0, acc[0][0], 0, 0, 0);
            acc[1][0] = __builtin_amdgcn_mfma_f32_16x16x32_bf16(af1, b0, acc[1][0], 0, 0, 0);
            acc[0][1] = __builtin_amdgcn_mfma_f32_16x16x32_bf16(af0, b1, acc[0][1], 0, 0, 0);
            acc[1][1] = __builtin_amdgcn_mfma_f32_16x16x32_bf16(af1, b1, acc[1][1], 0, 0, 0);
            acc[0][2] = __builtin_amdgcn_mfma_f32_16x16x32_bf16(af0, b2, acc[0][2], 0, 0, 0);
            acc[1][2] = __builtin_amdgcn_mfma_f32_16x16x32_bf16(af1, b2, acc[1][2], 0, 0, 0);
            acc[0][3] = __builtin_amdgcn_mfma_f32_16x16x32_bf16(af0, b3, acc[0][3], 0, 0, 0);
            acc[1][3] = __builtin_amdgcn_mfma_f32_16x16x32_bf16(af1, b3, acc[1][3], 0, 0, 0);
            accl[0] = __builtin_amdgcn_mfma_f32_16x16x32_bf16(af0, ones, accl[0], 0, 0, 0);
            accl[1] = __builtin_amdgcn_mfma_f32_16x16x32_bf16(af1, ones, accl[1], 0, 0, 0);
        }
    }
    // ---- end-of-kernel reduction across the 4 j-quarter waves (LDS) ----
    __shared__ float lred[4 * 32];                   // [wave][row32]
    __shared__ float lsum[32];                       // 1/l per row
    __shared__ float red[4 * 2 * 16 * 17];           // [wave][f][r16][c16 pad17]
    if (lrw == 0) {
#pragma unroll
        for (int f = 0; f < 2; f++)
#pragma unroll
            for (int r = 0; r < 4; r++)
                lred[wave * 32 + f * 16 + quad * 4 + r] = accl[f][r];
    }
    __syncthreads();
    if (tid < 32)
        lsum[tid] = 1.0f / (lred[tid] + lred[32 + tid] + lred[64 + tid] + lred[96 + tid]);
    __syncthreads();
    for (int ct = 0; ct < 4; ct++) {
#pragma unroll
        for (int f = 0; f < 2; f++)
#pragma unroll
            for (int r = 0; r < 4; r++)
                red[wave * 544 + f * 272 + (quad * 4 + r) * 17 + lrw] = acc[f][ct][r];
        __syncthreads();
#pragma unroll
        for (int k = 0; k < 2; k++) {
            int pos = k * 256 + tid;                 // [0,512): f(1b) r16(4b) c16(4b)
            int f = pos >> 8, r16 = (pos >> 4) & 15, c16 = pos & 15;
            int bse = f * 272 + r16 * 17 + c16;
            float sum = red[bse] + red[bse + 544] + red[bse + 1088] + red[bse + 1632];
            float v = sum * lsum[f * 16 + r16];
            v = v > 0.f ? v : 0.f;
            int row = i0 + f * 16 + r16;
            size_t o = ((size_t)(b * GN) + row) * GHF + hh * 64 + ct * 16 + c16;
            if (isf) ((float*)outv)[o] = v;
            else     ((unsigned short*)outv)[o] = gat_f2bf(v);
        }
        __syncthreads();
    }
#else
    // correctness-only fallback: thread -> (row = tid>>3, 8-col eighth)
    int row = i0 + (tid >> 3), chh = (tid & 7) * 8;
    const unsigned short* hbb = hswz + (size_t)(bh * 64) * GN;  // per-bh slice
    const unsigned int* mr = mask32 + ((size_t)(b * GN) + row) * 64;
    float s = att_s[bh * GN + row];
    float z = s + maxn;
    float c = fmaxf(z, 0.2f * z);
    float k1 = __expf(s - c), k2 = __expf(0.2f * s - c);
    float l = 0.f;
    float accS[8] = {};
    for (int j = 0; j < GN; j++) {
        if (!((mr[j >> 5] >> (j & 31)) & 1u)) continue;
        unsigned int word = Tp[j];
        float Ev  = __uint_as_float(word & 0xffff0000u);
        float E5v = __uint_as_float(word << 16);
        float p = fmaxf(k1 * Ev, k2 * E5v);
        union { float f; unsigned int u; } t; t.f = p; t.u &= 0xffff0000u;
        l += t.f;
        for (int cc = 0; cc < 8; cc++)
            accS[cc] += t.f * gat_bf2f(hbb[gat_hswz_idx(chh + cc, j)]);
    }
    float li = 1.0f / l;
    for (int cc = 0; cc < 8; cc++) {
        float v = accS[cc] * li; v = v > 0.f ? v : 0.f;
        size_t oi = ((size_t)(b * GN) + row) * GHF + hh * 64 + chh + cc;
        if (isf) ((float*)outv)[oi] = v;
        else     ((unsigned short*)outv)[oi] = gat_f2bf(v);
    }
#endif
}

// --------------------------------------------------------------------------
extern "C" void kernel_launch(void* const* d_in, const int* in_sizes, int n_in,
                              void* d_out, int out_size, void* d_ws, size_t ws_size,
                              hipStream_t stream) {
    const void* X  = d_in[0];
    const void* A  = d_in[1];
    const void* W  = d_in[2];
    const void* aS = d_in[3];
    const void* aN = d_in[4];

    char* ws = (char*)d_ws;
    unsigned short* hswz = (unsigned short*)(ws + OFF_HS);
    float* att_s = (float*)(ws + OFF_ATTS);
    unsigned int* Tb = (unsigned int*)(ws + OFF_TB);
    unsigned long long* mask = (unsigned long long*)(ws + OFF_MASK);
    unsigned int* maxn_enc = (unsigned int*)(ws + OFF_MAXN);
    unsigned short* Xc = (unsigned short*)(ws + OFF_XC);
    unsigned short* Wc = (unsigned short*)(ws + OFF_WC);

    k_mask_conv<<<9280, 256, 0, stream>>>(A, X, W, mask, maxn_enc, Xc, Wc);
    k_gemm1<<<1024, 256, 0, stream>>>(Xc, Wc, aS, aN, (const float*)A,
                                      hswz, att_s, Tb, maxn_enc);
    k_attn_av<<<2048, 256, 0, stream>>>((const unsigned int*)mask, hswz,
                                        att_s, Tb, maxn_enc,
                                        (const float*)A, d_out);
}